// Round 10
// baseline (206.564 us; speedup 1.0000x reference)
//
#include <hip/hip_runtime.h>

// ---------------------------------------------------------------------------
// NearestSim: out[t] = -cos(q_t, items[argmax_j q_t . items_j])
// T=16384, M=4096, C=512, fp32 in/out.
// fp16 MFMA fused GEMM + packed (score|idx) top-2, exact fp32 rescue.
// R10: TLP round. R9 proved no pipe >40% busy at 2.4 waves/SIMD -> latency
// bound. Wave tile 32x64 (acc 32 AGPR, ~85 regs), single 12 KB LDS buffer
// -> 5-6 waves/SIMD. LDS-read pipe becomes the wall (~147k cyc/CU = 61 us).
// Keeps R9's conflict-free XOR swizzle (measured 0 conflicts) + packed idx.
// ---------------------------------------------------------------------------

#define TQ 16384
#define MI 4096
#define CD 512
#define NSPLIT 64       // item-space chunks of 64
#define BM 128          // block query rows (4 waves x 32)
#define BN 64           // block item cols
#define KITER (CD / 32) // 16 k-steps of 32

typedef _Float16 half8   __attribute__((ext_vector_type(8)));
typedef _Float16 half4_t __attribute__((ext_vector_type(4)));
typedef float    float4t __attribute__((ext_vector_type(4)));

// workspace layout (bytes)
#define QH_OFF   (0u)
#define QH_BYTES ((unsigned)TQ * CD * 2u)          // 16 MB fp16 queries
#define IH_OFF   (QH_OFF + QH_BYTES)
#define IH_BYTES ((unsigned)MI * CD * 2u)          // 4 MB fp16 items
#define PART_OFF (IH_OFF + IH_BYTES)
#define PART_BYTES ((unsigned)TQ * 64u * 8u)       // 8 MB: 64 float2 / query
// total 28 MB

__device__ __forceinline__ void lds_load16(const void* g, void* l) {
  __builtin_amdgcn_global_load_lds(
      (const __attribute__((address_space(1))) void*)g,
      (__attribute__((address_space(3))) void*)l, 16, 0, 0);
}

// ---------------- kernel 1: fp32 -> fp16 conversion (row-major) -------------
__global__ __launch_bounds__(256) void convert_kernel(
    const float* __restrict__ q, const float* __restrict__ it,
    char* __restrict__ ws) {
  int idx = blockIdx.x * 256 + threadIdx.x;
  const int QV = TQ * CD / 4;
  const int IV = MI * CD / 4;
  half4_t* Qh = (half4_t*)(ws + QH_OFF);
  half4_t* Ih = (half4_t*)(ws + IH_OFF);
  if (idx < QV) {
    float4 v = ((const float4*)q)[idx];
    half4_t h = {(_Float16)v.x, (_Float16)v.y, (_Float16)v.z, (_Float16)v.w};
    Qh[idx] = h;
  }
  if (idx < IV) {
    float4 v = ((const float4*)it)[idx];
    half4_t h = {(_Float16)v.x, (_Float16)v.y, (_Float16)v.z, (_Float16)v.w};
    Ih[idx] = h;
  }
}

// ---------------- kernel 2: fused fp16 GEMM + packed top-2 ------------------
// grid (TQ/BM, MI/BN), block 256 = 4 waves stacked in q; wave tile 32q x 64i
// (2x4 grid of 16x16x32 MFMAs, 32 AGPR acc). Single-buffer staging,
// 2 barriers per kk; 5-6 blocks/CU.
// LDS image: phys(row, chunk16) = row*64 + ((chunk ^ ((row>>1)&3))*16)
// -> conflict-free b128 fragment reads (R9: measured 0 conflicts).
__global__ __launch_bounds__(256, 4) void score_kernel(char* __restrict__ ws) {
  __shared__ __align__(16) char sA[BM * 64];  // 8 KB (128 q rows x 32 fp16)
  __shared__ __align__(16) char sB[BN * 64];  // 4 KB (64 item rows)

  const int tid  = threadIdx.x;
  const int lane = tid & 63;
  const int wave = tid >> 6;
  const int quad = lane >> 4;
  const int l15  = lane & 15;
  const int qtile = blockIdx.x;
  const int split = blockIdx.y;

  const char* Qh = ws + QH_OFF;
  const char* Ih = ws + IH_OFF;

  // staging: thread t stages the gmem chunk landing at phys t*16 (+4096 for
  // A rows 64..127): row = t>>2, phys chunk = t&3,
  // logical chunk = (t&3) ^ ((row>>1)&3) = (t&3) ^ ((t>>3)&3).
  const int qlog = (tid & 3) ^ ((tid >> 3) & 3);
  const int f = (tid >> 2) * 1024 + qlog * 16;           // gmem offset pattern
  const char* gA0 = Qh + (size_t)qtile * BM * 1024 + f;  // q rows 0..63
  const char* gA1 = gA0 + 64 * 1024;                     // q rows 64..127
  const char* gB0 = Ih + (size_t)split * BN * 1024 + f;  // item rows 0..63
  const int flat = tid * 16;  // LDS dest (wave-uniform base + lane*16)

  // fragment offsets: A row = wave*32 + mi*16 + l15; B row = ni*16 + l15
  const int swz = (l15 >> 1) & 3;
  const int aBase = (wave * 32 + l15) * 64 + ((quad ^ swz) * 16);  // + mi*1024
  const int bBase = l15 * 64 + ((quad ^ swz) * 16);                // + ni*1024

  float4t acc[2][4];
#pragma unroll
  for (int mi = 0; mi < 2; ++mi)
#pragma unroll
    for (int ni = 0; ni < 4; ++ni) acc[mi][ni] = (float4t){0.f, 0.f, 0.f, 0.f};

#pragma unroll
  for (int kk = 0; kk < KITER; ++kk) {
    const int kb = kk * 64;  // 32 fp16 = 64 B per k-slice
    __syncthreads();         // previous step's fragment reads complete
    lds_load16(gA0 + kb, sA + flat);
    lds_load16(gA1 + kb, sA + flat + 4096);
    lds_load16(gB0 + kb, sB + flat);
    __syncthreads();         // staged data visible (compiler drains vmcnt)

    half8 a[2], b[4];
#pragma unroll
    for (int mi = 0; mi < 2; ++mi)
      a[mi] = *(const half8*)(sA + aBase + mi * 1024);
#pragma unroll
    for (int ni = 0; ni < 4; ++ni)
      b[ni] = *(const half8*)(sB + bBase + ni * 1024);
#pragma unroll
    for (int mi = 0; mi < 2; ++mi)
#pragma unroll
      for (int ni = 0; ni < 4; ++ni)
        acc[mi][ni] = __builtin_amdgcn_mfma_f32_16x16x32_f16(
            a[mi], b[ni], acc[mi][ni], 0, 0, 0);
  }

  // ---- epilogue: packed (score | global idx) top-2, per query row ----
  // C row = quad*4+r, col = l15. Global item = split*64 + ni*16 + l15 < 4096
  // fits 12 bits; quantizing score to 2^12 ulp (<=0.03 abs vs gap ~5.5) is
  // harmless (any flip is between items whose cosines agree to ~1e-4).
  float t1[8], t2[8];
#pragma unroll
  for (int s = 0; s < 8; ++s) { t1[s] = -1e30f; t2[s] = -1e30f; }

  const int locBase = split * 64 + l15;
#pragma unroll
  for (int ni = 0; ni < 4; ++ni) {
    const int loc = locBase + ni * 16;
#pragma unroll
    for (int mi = 0; mi < 2; ++mi) {
#pragma unroll
      for (int r = 0; r < 4; ++r) {
        const int s = mi * 4 + r;
        const int pb = (__float_as_int(acc[mi][ni][r]) & 0xFFFFF000) | loc;
        const float pv = __int_as_float(pb);
        const float mn = fminf(t1[s], pv);
        t1[s] = fmaxf(t1[s], pv);
        t2[s] = fmaxf(t2[s], mn);
      }
    }
  }

  // 4-step butterfly across the 16-lane l15 group (pure fmin/fmax)
#pragma unroll
  for (int s = 0; s < 8; ++s) {
#pragma unroll
    for (int m = 1; m < 16; m <<= 1) {
      const float o1 = __shfl_xor(t1[s], m, 16);
      const float o2 = __shfl_xor(t2[s], m, 16);
      const float mn = fminf(t1[s], o1);
      t1[s] = fmaxf(t1[s], o1);
      t2[s] = fmaxf(fmaxf(t2[s], o2), mn);
    }
  }

  // writer: l15 == 0; one entry per (qrow, split); waves cover disjoint qrows.
  if (l15 == 0) {
    float2* part = (float2*)(ws + PART_OFF);
#pragma unroll
    for (int s = 0; s < 8; ++s) {
      const int qrow = qtile * BM + wave * 32 + (s >> 2) * 16 + quad * 4 + (s & 3);
      part[(size_t)qrow * 64 + split] = make_float2(t1[s], t2[s]);
    }
  }
}

// ---------------- kernel 3: merge partials + exact fp32 rescue --------------
// one wave per query: 64 packed entries (1/lane) -> global fp16 top-2 ->
// exact fp32 re-score of both candidates from the ORIGINAL fp32 inputs.
__global__ __launch_bounds__(256) void rescue_kernel(
    const float* __restrict__ q, const float* __restrict__ items,
    const char* __restrict__ ws, float* __restrict__ out) {
  const int wave = threadIdx.x >> 6;
  const int lane = threadIdx.x & 63;
  const int qrow = blockIdx.x * 4 + wave;

  const float2* part = (const float2*)(ws + PART_OFF);
  float2 ent = part[(size_t)qrow * 64 + lane];  // coalesced 512B burst
  float t1 = ent.x, t2 = ent.y;

#pragma unroll
  for (int m = 1; m < 64; m <<= 1) {
    const float o1 = __shfl_xor(t1, m, 64);
    const float o2 = __shfl_xor(t2, m, 64);
    const float mn = fminf(t1, o1);
    t1 = fmaxf(t1, o1);
    t2 = fmaxf(fmaxf(t2, o2), mn);
  }
  const int c1i = __float_as_int(t1) & 0xFFF;
  const int c2i = __float_as_int(t2) & 0xFFF;

  const float4* qp = (const float4*)(q + (size_t)qrow * CD);
  const float4* p1 = (const float4*)(items + (size_t)c1i * CD);
  const float4* p2 = (const float4*)(items + (size_t)c2i * CD);
  float4 qa = qp[lane * 2], qb = qp[lane * 2 + 1];
  float4 xa = p1[lane * 2], xb = p1[lane * 2 + 1];
  float4 ya = p2[lane * 2], yb = p2[lane * 2 + 1];

  float d1 = qa.x * xa.x + qa.y * xa.y + qa.z * xa.z + qa.w * xa.w +
             qb.x * xb.x + qb.y * xb.y + qb.z * xb.z + qb.w * xb.w;
  float d2 = qa.x * ya.x + qa.y * ya.y + qa.z * ya.z + qa.w * ya.w +
             qb.x * yb.x + qb.y * yb.y + qb.z * yb.z + qb.w * yb.w;
  float qq = qa.x * qa.x + qa.y * qa.y + qa.z * qa.z + qa.w * qa.w +
             qb.x * qb.x + qb.y * qb.y + qb.z * qb.z + qb.w * qb.w;
  float i1 = xa.x * xa.x + xa.y * xa.y + xa.z * xa.z + xa.w * xa.w +
             xb.x * xb.x + xb.y * xb.y + xb.z * xb.z + xb.w * xb.w;
  float i2 = ya.x * ya.x + ya.y * ya.y + ya.z * ya.z + ya.w * ya.w +
             yb.x * yb.x + yb.y * yb.y + yb.z * yb.z + yb.w * yb.w;

#pragma unroll
  for (int m = 1; m < 64; m <<= 1) {
    d1 += __shfl_xor(d1, m, 64);
    d2 += __shfl_xor(d2, m, 64);
    qq += __shfl_xor(qq, m, 64);
    i1 += __shfl_xor(i1, m, 64);
    i2 += __shfl_xor(i2, m, 64);
  }

  if (lane == 0) {
    bool use2 = (d2 > d1) || (d2 == d1 && c2i < c1i);
    float d  = use2 ? d2 : d1;
    float nn = use2 ? i2 : i1;
    float nq = fmaxf(sqrtf(qq), 1e-12f);
    float np = fmaxf(sqrtf(nn), 1e-12f);
    out[qrow] = -(d / (nq * np));
  }
}

// ---------------------------------------------------------------------------
extern "C" void kernel_launch(void* const* d_in, const int* in_sizes, int n_in,
                              void* d_out, int out_size, void* d_ws,
                              size_t ws_size, hipStream_t stream) {
  const float* q  = (const float*)d_in[0];
  const float* it = (const float*)d_in[1];
  char* ws = (char*)d_ws;
  float* out = (float*)d_out;

  convert_kernel<<<TQ * CD / 4 / 256, 256, 0, stream>>>(q, it, ws);
  dim3 grid(TQ / BM, MI / BN);
  score_kernel<<<grid, 256, 0, stream>>>(ws);
  rescue_kernel<<<TQ / 4, 256, 0, stream>>>(q, it, ws, out);
}

// Round 11
// 182.637 us; speedup vs baseline: 1.1310x; 1.1310x over previous
//
#include <hip/hip_runtime.h>

// ---------------------------------------------------------------------------
// NearestSim: out[t] = -cos(q_t, items[argmax_j q_t . items_j])
// T=16384, M=4096, C=512, fp32 in/out.
// R11: barrier-free K-loop. A (queries) staged ONCE per block into LDS
// (64 rows x 512 cols fp16 = 64 KB, XOR-swizzled -> conflict-free b128);
// B (items) read directly from global in fragment order (coalesced 1KB/instr,
// 4 MB total -> L2-hot). Depth-1 software pipeline, NO __syncthreads in the
// K-loop -> compiler can keep loads in flight (vmcnt(N), not vmcnt(0)).
// R7/R9/R10 proved the 2-barrier-per-kk skeleton plateaus at ~108 us
// regardless of conflicts/occupancy/tile -- this restructures it away.
// ---------------------------------------------------------------------------

#define TQ 16384
#define MI 4096
#define CD 512
#define NIS 16          // item splits; block covers 256 items
#define BM 64           // block query rows
#define KITER (CD / 32) // 16 k-steps of 32

typedef _Float16 half8   __attribute__((ext_vector_type(8)));
typedef _Float16 half4_t __attribute__((ext_vector_type(4)));
typedef float    float4t __attribute__((ext_vector_type(4)));

// workspace layout (bytes)
#define QH_OFF   (0u)
#define QH_BYTES ((unsigned)TQ * CD * 2u)          // 16 MB fp16 queries (row-major)
#define IH_OFF   (QH_OFF + QH_BYTES)
#define IH_BYTES ((unsigned)MI * CD * 2u)          // 4 MB fp16 items (fragment order)
#define PART_OFF (IH_OFF + IH_BYTES)
#define PART_BYTES ((unsigned)TQ * 64u * 8u)       // 8 MB: 64 float2 / query
// total 28 MB

__device__ __forceinline__ void lds_load16(const void* g, void* l) {
  __builtin_amdgcn_global_load_lds(
      (const __attribute__((address_space(1))) void*)g,
      (__attribute__((address_space(3))) void*)l, 16, 0, 0);
}

// ---------------- kernel 1: fp32 -> fp16 conversion -------------------------
// Q: row-major half4 copy. Items: fragment order (chunk = (tile16*16+kk)*64
// + lane; lane = quad*16+l15 holds row tile16*16+l15, cols kk*32+quad*8..+8)
// -- layout correctness proven in R5.
__global__ __launch_bounds__(256) void convert_kernel(
    const float* __restrict__ q, const float* __restrict__ it,
    char* __restrict__ ws) {
  const int idx = blockIdx.x * 256 + threadIdx.x;
  const int QV = TQ * CD / 4;   // Q: one half4 per thread
  const int IC = MI * CD / 8;   // items: one 16B chunk per thread
  if (idx < QV) {
    float4 v = ((const float4*)q)[idx];
    half4_t h = {(_Float16)v.x, (_Float16)v.y, (_Float16)v.z, (_Float16)v.w};
    ((half4_t*)(ws + QH_OFF))[idx] = h;
  }
  const int ic = idx - QV;
  if (ic >= 0 && ic < IC) {
    const int tile = ic >> 10;          // 1024 chunks per 16-row tile
    const int rem  = ic & 1023;
    const int kk   = rem >> 6;
    const int lane = rem & 63;
    const int row  = tile * 16 + (lane & 15);
    const int col  = kk * 32 + (lane >> 4) * 8;
    const float4* s = (const float4*)(it + (size_t)row * CD + col);
    float4 v0 = s[0], v1 = s[1];
    half8 h = {(_Float16)v0.x, (_Float16)v0.y, (_Float16)v0.z, (_Float16)v0.w,
               (_Float16)v1.x, (_Float16)v1.y, (_Float16)v1.z, (_Float16)v1.w};
    *(half8*)(ws + IH_OFF + (size_t)ic * 16) = h;
  }
}

// ---------------- kernel 2: barrier-free fused GEMM + packed top-2 ----------
// grid (TQ/BM, NIS), block 256 = 4 waves; wave tile 64q x 64i (4x4 MFMAs,
// 64 AGPR acc). A from LDS (staged once), B direct from global.
// LDS image: phys(row, chunk16) = row*1024 + ((chunk ^ (row&7))*16)
// -> b128 reads conflict-free (XOR is a bijection on each 8-lane phase).
__global__ __launch_bounds__(256) void score_kernel(char* __restrict__ ws) {
  __shared__ __align__(16) char sA[BM * 1024];  // 64 KB: 64 rows x 512 fp16

  const int tid  = threadIdx.x;
  const int lane = tid & 63;
  const int wave = tid >> 6;
  const int quad = lane >> 4;
  const int l15  = lane & 15;
  const int qtile = blockIdx.x;
  const int isplit = blockIdx.y;

  // ---- stage A once: 16 x global_load_lds, then one barrier ----
  const char* Qbase = ws + QH_OFF + (size_t)qtile * BM * 1024;
#pragma unroll
  for (int j = 0; j < 16; ++j) {
    const int row = wave + j * 4;        // each (wave,j) stages one 1KB row
    const int swz = row & 7;             // wave-uniform
    lds_load16(Qbase + row * 1024 + ((lane ^ swz) * 16),
               sA + wave * 1024 + j * 4096 + lane * 16);
  }

  // B fragment pointers: tile(ni) = isplit*16 + wave*4 + ni
  const char* Ibase = ws + IH_OFF;
  const char* bP[4];
#pragma unroll
  for (int ni = 0; ni < 4; ++ni)
    bP[ni] = Ibase + ((size_t)(isplit * 16 + wave * 4 + ni) * 16384) + lane * 16;

  // A fragment offsets: row = mi*16 + l15, chunk = kk*4+quad, swz by l15&7
  const int aRow = l15 * 1024;
  const int swzl = l15 & 7;

  float4t acc[4][4];
#pragma unroll
  for (int mi = 0; mi < 4; ++mi)
#pragma unroll
    for (int ni = 0; ni < 4; ++ni) acc[mi][ni] = (float4t){0.f, 0.f, 0.f, 0.f};

  __syncthreads();  // the ONLY barrier: A image complete

  // ---- K-loop: no barriers; depth-1 software pipeline ----
  half8 aC[4], bC[4], aN[4], bN[4];
  {
    const int c0 = ((quad ^ swzl) << 4);  // kk=0 chunk offset
#pragma unroll
    for (int mi = 0; mi < 4; ++mi)
      aC[mi] = *(const half8*)(sA + aRow + mi * 16384 + c0);
#pragma unroll
    for (int ni = 0; ni < 4; ++ni) bC[ni] = *(const half8*)(bP[ni]);
  }

#pragma unroll
  for (int kk = 0; kk < KITER; ++kk) {
    if (kk + 1 < KITER) {
      const int cN = ((((kk + 1) << 2) + quad) ^ swzl) << 4;
#pragma unroll
      for (int mi = 0; mi < 4; ++mi)
        aN[mi] = *(const half8*)(sA + aRow + mi * 16384 + cN);
#pragma unroll
      for (int ni = 0; ni < 4; ++ni)
        bN[ni] = *(const half8*)(bP[ni] + (kk + 1) * 1024);
    }
#pragma unroll
    for (int mi = 0; mi < 4; ++mi)
#pragma unroll
      for (int ni = 0; ni < 4; ++ni)
        acc[mi][ni] = __builtin_amdgcn_mfma_f32_16x16x32_f16(
            aC[mi], bC[ni], acc[mi][ni], 0, 0, 0);
#pragma unroll
    for (int x = 0; x < 4; ++x) { aC[x] = aN[x]; bC[x] = bN[x]; }
  }

  // ---- epilogue: packed (score | 12-bit global idx) top-2 per query row ----
  // C row = quad*4+r, col = l15. item = isplit*256 + wave*64 + ni*16 + l15.
  float t1[16], t2[16];
#pragma unroll
  for (int s = 0; s < 16; ++s) { t1[s] = -1e30f; t2[s] = -1e30f; }

  const int locBase = isplit * 256 + wave * 64 + l15;
#pragma unroll
  for (int ni = 0; ni < 4; ++ni) {
    const int loc = locBase + ni * 16;
#pragma unroll
    for (int mi = 0; mi < 4; ++mi) {
#pragma unroll
      for (int r = 0; r < 4; ++r) {
        const int s = mi * 4 + r;
        const int pb = (__float_as_int(acc[mi][ni][r]) & 0xFFFFF000) | loc;
        const float pv = __int_as_float(pb);
        const float mn = fminf(t1[s], pv);
        t1[s] = fmaxf(t1[s], pv);
        t2[s] = fmaxf(t2[s], mn);
      }
    }
  }

  // 4-step butterfly across the 16-lane l15 group (pure fmin/fmax)
#pragma unroll
  for (int s = 0; s < 16; ++s) {
#pragma unroll
    for (int m = 1; m < 16; m <<= 1) {
      const float o1 = __shfl_xor(t1[s], m, 16);
      const float o2 = __shfl_xor(t2[s], m, 16);
      const float mn = fminf(t1[s], o1);
      t1[s] = fmaxf(t1[s], o1);
      t2[s] = fmaxf(fmaxf(t2[s], o2), mn);
    }
  }

  // writer: l15 == 0; entry = isplit*4 + wave (waves cover disjoint items,
  // same qrows -> disjoint entries). 64 entries per query.
  if (l15 == 0) {
    float2* part = (float2*)(ws + PART_OFF);
    const int e = isplit * 4 + wave;
#pragma unroll
    for (int s = 0; s < 16; ++s) {
      const int qrow = qtile * BM + (s >> 2) * 16 + quad * 4 + (s & 3);
      part[(size_t)qrow * 64 + e] = make_float2(t1[s], t2[s]);
    }
  }
}

// ---------------- kernel 3: merge partials + exact fp32 rescue --------------
// one wave per query: 64 packed entries (1/lane) -> global fp16 top-2 ->
// exact fp32 re-score of both candidates from the ORIGINAL fp32 inputs.
__global__ __launch_bounds__(256) void rescue_kernel(
    const float* __restrict__ q, const float* __restrict__ items,
    const char* __restrict__ ws, float* __restrict__ out) {
  const int wave = threadIdx.x >> 6;
  const int lane = threadIdx.x & 63;
  const int qrow = blockIdx.x * 4 + wave;

  const float2* part = (const float2*)(ws + PART_OFF);
  float2 ent = part[(size_t)qrow * 64 + lane];  // coalesced 512B burst
  float t1 = ent.x, t2 = ent.y;

#pragma unroll
  for (int m = 1; m < 64; m <<= 1) {
    const float o1 = __shfl_xor(t1, m, 64);
    const float o2 = __shfl_xor(t2, m, 64);
    const float mn = fminf(t1, o1);
    t1 = fmaxf(t1, o1);
    t2 = fmaxf(fmaxf(t2, o2), mn);
  }
  const int c1i = __float_as_int(t1) & 0xFFF;
  const int c2i = __float_as_int(t2) & 0xFFF;

  const float4* qp = (const float4*)(q + (size_t)qrow * CD);
  const float4* p1 = (const float4*)(items + (size_t)c1i * CD);
  const float4* p2 = (const float4*)(items + (size_t)c2i * CD);
  float4 qa = qp[lane * 2], qb = qp[lane * 2 + 1];
  float4 xa = p1[lane * 2], xb = p1[lane * 2 + 1];
  float4 ya = p2[lane * 2], yb = p2[lane * 2 + 1];

  float d1 = qa.x * xa.x + qa.y * xa.y + qa.z * xa.z + qa.w * xa.w +
             qb.x * xb.x + qb.y * xb.y + qb.z * xb.z + qb.w * xb.w;
  float d2 = qa.x * ya.x + qa.y * ya.y + qa.z * ya.z + qa.w * ya.w +
             qb.x * yb.x + qb.y * yb.y + qb.z * yb.z + qb.w * yb.w;
  float qq = qa.x * qa.x + qa.y * qa.y + qa.z * qa.z + qa.w * qa.w +
             qb.x * qb.x + qb.y * qb.y + qb.z * qb.z + qb.w * qb.w;
  float i1 = xa.x * xa.x + xa.y * xa.y + xa.z * xa.z + xa.w * xa.w +
             xb.x * xb.x + xb.y * xb.y + xb.z * xb.z + xb.w * xb.w;
  float i2 = ya.x * ya.x + ya.y * ya.y + ya.z * ya.z + ya.w * ya.w +
             yb.x * yb.x + yb.y * yb.y + yb.z * yb.z + yb.w * yb.w;

#pragma unroll
  for (int m = 1; m < 64; m <<= 1) {
    d1 += __shfl_xor(d1, m, 64);
    d2 += __shfl_xor(d2, m, 64);
    qq += __shfl_xor(qq, m, 64);
    i1 += __shfl_xor(i1, m, 64);
    i2 += __shfl_xor(i2, m, 64);
  }

  if (lane == 0) {
    bool use2 = (d2 > d1) || (d2 == d1 && c2i < c1i);
    float d  = use2 ? d2 : d1;
    float nn = use2 ? i2 : i1;
    float nq = fmaxf(sqrtf(qq), 1e-12f);
    float np = fmaxf(sqrtf(nn), 1e-12f);
    out[qrow] = -(d / (nq * np));
  }
}

// ---------------------------------------------------------------------------
extern "C" void kernel_launch(void* const* d_in, const int* in_sizes, int n_in,
                              void* d_out, int out_size, void* d_ws,
                              size_t ws_size, hipStream_t stream) {
  const float* q  = (const float*)d_in[0];
  const float* it = (const float*)d_in[1];
  char* ws = (char*)d_ws;
  float* out = (float*)d_out;

  const int total = TQ * CD / 4 + MI * CD / 8;
  convert_kernel<<<(total + 255) / 256, 256, 0, stream>>>(q, it, ws);
  dim3 grid(TQ / BM, NIS);
  score_kernel<<<grid, 256, 0, stream>>>(ws);
  rescue_kernel<<<TQ / 4, 256, 0, stream>>>(q, it, ws, out);
}

// Round 12
// 176.749 us; speedup vs baseline: 1.1687x; 1.0333x over previous
//
#include <hip/hip_runtime.h>

// ---------------------------------------------------------------------------
// NearestSim: out[t] = -cos(q_t, items[argmax_j q_t . items_j])
// T=16384, M=4096, C=512, fp32 in/out.
// R12: R11's barrier-free K-loop (score 97.6us, WIN) + half-K LDS phases:
// A image = 32 KB (64 rows x 256 cols fp16) staged twice per block ->
// occupancy limiter moves from LDS (2 blocks/CU) to regs (3 blocks/CU,
// 164 unified <= 170 cap). Barriers: 4/block total, inner loops barrier-free.
// B (items) direct from global in fragment order (R5-proven layout), depth-1
// register prefetch for both a and b.
// ---------------------------------------------------------------------------

#define TQ 16384
#define MI 4096
#define CD 512
#define NIS 16          // item splits; block covers 256 items
#define BM 64           // block query rows
#define KHALF 8         // k-steps per phase (of 32 each)

typedef _Float16 half8   __attribute__((ext_vector_type(8)));
typedef _Float16 half4_t __attribute__((ext_vector_type(4)));
typedef float    float4t __attribute__((ext_vector_type(4)));

// workspace layout (bytes)
#define QH_OFF   (0u)
#define QH_BYTES ((unsigned)TQ * CD * 2u)          // 16 MB fp16 queries (row-major)
#define IH_OFF   (QH_OFF + QH_BYTES)
#define IH_BYTES ((unsigned)MI * CD * 2u)          // 4 MB fp16 items (fragment order)
#define PART_OFF (IH_OFF + IH_BYTES)
#define PART_BYTES ((unsigned)TQ * 64u * 8u)       // 8 MB: 64 float2 / query
// total 28 MB

__device__ __forceinline__ void lds_load16(const void* g, void* l) {
  __builtin_amdgcn_global_load_lds(
      (const __attribute__((address_space(1))) void*)g,
      (__attribute__((address_space(3))) void*)l, 16, 0, 0);
}

// ---------------- kernel 1: fp32 -> fp16 conversion -------------------------
// Q: row-major half4 copy. Items: fragment order (chunk = (tile16*16+kk)*64
// + lane; lane = quad*16+l15 holds row tile16*16+l15, cols kk*32+quad*8..+8).
__global__ __launch_bounds__(256) void convert_kernel(
    const float* __restrict__ q, const float* __restrict__ it,
    char* __restrict__ ws) {
  const int idx = blockIdx.x * 256 + threadIdx.x;
  const int QV = TQ * CD / 4;   // Q: one half4 per thread
  const int IC = MI * CD / 8;   // items: one 16B chunk per thread
  if (idx < QV) {
    float4 v = ((const float4*)q)[idx];
    half4_t h = {(_Float16)v.x, (_Float16)v.y, (_Float16)v.z, (_Float16)v.w};
    ((half4_t*)(ws + QH_OFF))[idx] = h;
  }
  const int ic = idx - QV;
  if (ic >= 0 && ic < IC) {
    const int tile = ic >> 10;          // 1024 chunks per 16-row tile
    const int rem  = ic & 1023;
    const int kk   = rem >> 6;
    const int lane = rem & 63;
    const int row  = tile * 16 + (lane & 15);
    const int col  = kk * 32 + (lane >> 4) * 8;
    const float4* s = (const float4*)(it + (size_t)row * CD + col);
    float4 v0 = s[0], v1 = s[1];
    half8 h = {(_Float16)v0.x, (_Float16)v0.y, (_Float16)v0.z, (_Float16)v0.w,
               (_Float16)v1.x, (_Float16)v1.y, (_Float16)v1.z, (_Float16)v1.w};
    *(half8*)(ws + IH_OFF + (size_t)ic * 16) = h;
  }
}

// ---------------- kernel 2: barrier-free fused GEMM + packed top-2 ----------
// grid (TQ/BM, NIS), block 256 = 4 waves; wave tile 64q x 64i (4x4 MFMAs,
// 64 AGPR acc). A half-K image in 32 KB LDS (two phases), B direct global.
// LDS image (per phase): phys(row, c) = row*512 + ((c ^ (row&7))*16), c=0..31
// -> b128 fragment reads conflict-free (XOR bijects each 8-lane phase).
__global__ __launch_bounds__(256, 3) void score_kernel(char* __restrict__ ws) {
  __shared__ __align__(16) char sA[BM * 512];  // 32 KB: 64 rows x 256 fp16

  const int tid  = threadIdx.x;
  const int lane = tid & 63;
  const int wave = tid >> 6;
  const int quad = lane >> 4;
  const int l15  = lane & 15;
  const int qtile = blockIdx.x;
  const int isplit = blockIdx.y;

  // staging map: instr j, thread t -> phys = j*4096 + t*16
  //   row = j*8 + (t>>5), c' = t&31, logical c = c' ^ (row&7) = (t&31)^((t>>5)&7)
  const char* Qbase = ws + QH_OFF + (size_t)qtile * BM * 1024;
  const int trow = tid >> 5;                       // 0..7
  const int cx   = (tid & 31) ^ (trow & 7);
  const char* gQ = Qbase + trow * 1024 + cx * 16;  // + phase*512 + j*8192
  const int ldst = wave * 1024 + lane * 16;        // + j*4096 (wave-uniform+lane*16)

  // B fragment pointers: tile(ni) = isplit*16 + wave*4 + ni (fragment order)
  const char* Ibase = ws + IH_OFF;
  const char* bP[4];
#pragma unroll
  for (int ni = 0; ni < 4; ++ni)
    bP[ni] = Ibase + ((size_t)(isplit * 16 + wave * 4 + ni) * 16384) + lane * 16;

  // A fragment offsets: row = mi*16 + l15 -> row*512 = mi*8192 + l15*512
  const int aRow = l15 * 512;
  const int swzl = l15 & 7;

  float4t acc[4][4];
#pragma unroll
  for (int mi = 0; mi < 4; ++mi)
#pragma unroll
    for (int ni = 0; ni < 4; ++ni) acc[mi][ni] = (float4t){0.f, 0.f, 0.f, 0.f};

  half8 aC[4], aN[4], bC[4], bN[4];
  // preload b(kk=0) while phase-0 staging is in flight
#pragma unroll
  for (int ni = 0; ni < 4; ++ni) bC[ni] = *(const half8*)(bP[ni]);

#pragma unroll
  for (int phase = 0; phase < 2; ++phase) {
    __syncthreads();  // phase 1: prior phase's a-frag reads complete
#pragma unroll
    for (int j = 0; j < 8; ++j)
      lds_load16(gQ + phase * 512 + j * 8192, sA + ldst + j * 4096);
    __syncthreads();  // staged image visible (compiler drains vmcnt)

    // preload a(kl=0)
    {
      const int c0 = (quad ^ swzl) << 4;
#pragma unroll
      for (int mi = 0; mi < 4; ++mi)
        aC[mi] = *(const half8*)(sA + aRow + mi * 8192 + c0);
    }

#pragma unroll
    for (int kl = 0; kl < KHALF; ++kl) {
      const int kk = phase * KHALF + kl;
      if (kl + 1 < KHALF) {
        const int cN = ((((kl + 1) << 2) + quad) ^ swzl) << 4;
#pragma unroll
        for (int mi = 0; mi < 4; ++mi)
          aN[mi] = *(const half8*)(sA + aRow + mi * 8192 + cN);
      }
      if (kk + 1 < 16) {
#pragma unroll
        for (int ni = 0; ni < 4; ++ni)
          bN[ni] = *(const half8*)(bP[ni] + (kk + 1) * 1024);
      }
#pragma unroll
      for (int mi = 0; mi < 4; ++mi)
#pragma unroll
        for (int ni = 0; ni < 4; ++ni)
          acc[mi][ni] = __builtin_amdgcn_mfma_f32_16x16x32_f16(
              aC[mi], bC[ni], acc[mi][ni], 0, 0, 0);
      if (kl + 1 < KHALF) {
#pragma unroll
        for (int x = 0; x < 4; ++x) aC[x] = aN[x];
      }
      if (kk + 1 < 16) {
#pragma unroll
        for (int x = 0; x < 4; ++x) bC[x] = bN[x];
      }
    }
  }

  // ---- epilogue: packed (score | 12-bit global idx) top-2 per query row ----
  // C row = quad*4+r, col = l15. item = isplit*256 + wave*64 + ni*16 + l15.
  float t1[16], t2[16];
#pragma unroll
  for (int s = 0; s < 16; ++s) { t1[s] = -1e30f; t2[s] = -1e30f; }

  const int locBase = isplit * 256 + wave * 64 + l15;
#pragma unroll
  for (int ni = 0; ni < 4; ++ni) {
    const int loc = locBase + ni * 16;
#pragma unroll
    for (int mi = 0; mi < 4; ++mi) {
#pragma unroll
      for (int r = 0; r < 4; ++r) {
        const int s = mi * 4 + r;
        const int pb = (__float_as_int(acc[mi][ni][r]) & 0xFFFFF000) | loc;
        const float pv = __int_as_float(pb);
        const float mn = fminf(t1[s], pv);
        t1[s] = fmaxf(t1[s], pv);
        t2[s] = fmaxf(t2[s], mn);
      }
    }
  }

  // 4-step butterfly across the 16-lane l15 group (pure fmin/fmax)
#pragma unroll
  for (int s = 0; s < 16; ++s) {
#pragma unroll
    for (int m = 1; m < 16; m <<= 1) {
      const float o1 = __shfl_xor(t1[s], m, 16);
      const float o2 = __shfl_xor(t2[s], m, 16);
      const float mn = fminf(t1[s], o1);
      t1[s] = fmaxf(t1[s], o1);
      t2[s] = fmaxf(fmaxf(t2[s], o2), mn);
    }
  }

  // writer: l15 == 0; entry = isplit*4 + wave (waves cover disjoint items,
  // same qrows -> disjoint entries). 64 entries per query.
  if (l15 == 0) {
    float2* part = (float2*)(ws + PART_OFF);
    const int e = isplit * 4 + wave;
#pragma unroll
    for (int s = 0; s < 16; ++s) {
      const int qrow = qtile * BM + (s >> 2) * 16 + quad * 4 + (s & 3);
      part[(size_t)qrow * 64 + e] = make_float2(t1[s], t2[s]);
    }
  }
}

// ---------------- kernel 3: merge partials + exact fp32 rescue --------------
// one wave per query: 64 packed entries (1/lane) -> global fp16 top-2 ->
// exact fp32 re-score of both candidates from the ORIGINAL fp32 inputs.
__global__ __launch_bounds__(256) void rescue_kernel(
    const float* __restrict__ q, const float* __restrict__ items,
    const char* __restrict__ ws, float* __restrict__ out) {
  const int wave = threadIdx.x >> 6;
  const int lane = threadIdx.x & 63;
  const int qrow = blockIdx.x * 4 + wave;

  const float2* part = (const float2*)(ws + PART_OFF);
  float2 ent = part[(size_t)qrow * 64 + lane];  // coalesced 512B burst
  float t1 = ent.x, t2 = ent.y;

#pragma unroll
  for (int m = 1; m < 64; m <<= 1) {
    const float o1 = __shfl_xor(t1, m, 64);
    const float o2 = __shfl_xor(t2, m, 64);
    const float mn = fminf(t1, o1);
    t1 = fmaxf(t1, o1);
    t2 = fmaxf(fmaxf(t2, o2), mn);
  }
  const int c1i = __float_as_int(t1) & 0xFFF;
  const int c2i = __float_as_int(t2) & 0xFFF;

  const float4* qp = (const float4*)(q + (size_t)qrow * CD);
  const float4* p1 = (const float4*)(items + (size_t)c1i * CD);
  const float4* p2 = (const float4*)(items + (size_t)c2i * CD);
  float4 qa = qp[lane * 2], qb = qp[lane * 2 + 1];
  float4 xa = p1[lane * 2], xb = p1[lane * 2 + 1];
  float4 ya = p2[lane * 2], yb = p2[lane * 2 + 1];

  float d1 = qa.x * xa.x + qa.y * xa.y + qa.z * xa.z + qa.w * xa.w +
             qb.x * xb.x + qb.y * xb.y + qb.z * xb.z + qb.w * xb.w;
  float d2 = qa.x * ya.x + qa.y * ya.y + qa.z * ya.z + qa.w * ya.w +
             qb.x * yb.x + qb.y * yb.y + qb.z * yb.z + qb.w * yb.w;
  float qq = qa.x * qa.x + qa.y * qa.y + qa.z * qa.z + qa.w * qa.w +
             qb.x * qb.x + qb.y * qb.y + qb.z * qb.z + qb.w * qb.w;
  float i1 = xa.x * xa.x + xa.y * xa.y + xa.z * xa.z + xa.w * xa.w +
             xb.x * xb.x + xb.y * xb.y + xb.z * xb.z + xb.w * xb.w;
  float i2 = ya.x * ya.x + ya.y * ya.y + ya.z * ya.z + ya.w * ya.w +
             yb.x * yb.x + yb.y * yb.y + yb.z * yb.z + yb.w * yb.w;

#pragma unroll
  for (int m = 1; m < 64; m <<= 1) {
    d1 += __shfl_xor(d1, m, 64);
    d2 += __shfl_xor(d2, m, 64);
    qq += __shfl_xor(qq, m, 64);
    i1 += __shfl_xor(i1, m, 64);
    i2 += __shfl_xor(i2, m, 64);
  }

  if (lane == 0) {
    bool use2 = (d2 > d1) || (d2 == d1 && c2i < c1i);
    float d  = use2 ? d2 : d1;
    float nn = use2 ? i2 : i1;
    float nq = fmaxf(sqrtf(qq), 1e-12f);
    float np = fmaxf(sqrtf(nn), 1e-12f);
    out[qrow] = -(d / (nq * np));
  }
}

// ---------------------------------------------------------------------------
extern "C" void kernel_launch(void* const* d_in, const int* in_sizes, int n_in,
                              void* d_out, int out_size, void* d_ws,
                              size_t ws_size, hipStream_t stream) {
  const float* q  = (const float*)d_in[0];
  const float* it = (const float*)d_in[1];
  char* ws = (char*)d_ws;
  float* out = (float*)d_out;

  const int total = TQ * CD / 4 + MI * CD / 8;
  convert_kernel<<<(total + 255) / 256, 256, 0, stream>>>(q, it, ws);
  dim3 grid(TQ / BM, NIS);
  score_kernel<<<grid, 256, 0, stream>>>(ws);
  rescue_kernel<<<TQ / 4, 256, 0, stream>>>(q, it, ws, out);
}

// Round 13
// 175.319 us; speedup vs baseline: 1.1782x; 1.0082x over previous
//
#include <hip/hip_runtime.h>

// ---------------------------------------------------------------------------
// NearestSim: out[t] = -cos(q_t, items[argmax_j q_t . items_j])
// T=16384, M=4096, C=512, fp32 in/out.
// R13 = R12 (barrier-free K-loop, half-K 32KB LDS A-image, 3 blocks/CU)
//  + depth-2 register prefetch on the global B stream (L2 ~200cyc latency
//    needs 2 kks of MFMA cover; R12's depth-1 left ~100cyc/kk exposed)
//  + gap-gated rescue: skip 2nd-candidate gather when packed top1-top2 gap
//    > 0.25 (5.7 sigma of the fp16+quant score error; wave-uniform branch).
// ---------------------------------------------------------------------------

#define TQ 16384
#define MI 4096
#define CD 512
#define NIS 16          // item splits; block covers 256 items
#define BM 64           // block query rows
#define KHALF 8         // k-steps per phase (of 32 each)

typedef _Float16 half8   __attribute__((ext_vector_type(8)));
typedef _Float16 half4_t __attribute__((ext_vector_type(4)));
typedef float    float4t __attribute__((ext_vector_type(4)));

// workspace layout (bytes)
#define QH_OFF   (0u)
#define QH_BYTES ((unsigned)TQ * CD * 2u)          // 16 MB fp16 queries (row-major)
#define IH_OFF   (QH_OFF + QH_BYTES)
#define IH_BYTES ((unsigned)MI * CD * 2u)          // 4 MB fp16 items (fragment order)
#define PART_OFF (IH_OFF + IH_BYTES)
#define PART_BYTES ((unsigned)TQ * 64u * 8u)       // 8 MB: 64 float2 / query
// total 28 MB

__device__ __forceinline__ void lds_load16(const void* g, void* l) {
  __builtin_amdgcn_global_load_lds(
      (const __attribute__((address_space(1))) void*)g,
      (__attribute__((address_space(3))) void*)l, 16, 0, 0);
}

// ---------------- kernel 1: fp32 -> fp16 conversion -------------------------
// Q: row-major half4 copy. Items: fragment order (chunk = (tile16*16+kk)*64
// + lane; lane = quad*16+l15 holds row tile16*16+l15, cols kk*32+quad*8..+8).
__global__ __launch_bounds__(256) void convert_kernel(
    const float* __restrict__ q, const float* __restrict__ it,
    char* __restrict__ ws) {
  const int idx = blockIdx.x * 256 + threadIdx.x;
  const int QV = TQ * CD / 4;   // Q: one half4 per thread
  const int IC = MI * CD / 8;   // items: one 16B chunk per thread
  if (idx < QV) {
    float4 v = ((const float4*)q)[idx];
    half4_t h = {(_Float16)v.x, (_Float16)v.y, (_Float16)v.z, (_Float16)v.w};
    ((half4_t*)(ws + QH_OFF))[idx] = h;
  }
  const int ic = idx - QV;
  if (ic >= 0 && ic < IC) {
    const int tile = ic >> 10;          // 1024 chunks per 16-row tile
    const int rem  = ic & 1023;
    const int kk   = rem >> 6;
    const int lane = rem & 63;
    const int row  = tile * 16 + (lane & 15);
    const int col  = kk * 32 + (lane >> 4) * 8;
    const float4* s = (const float4*)(it + (size_t)row * CD + col);
    float4 v0 = s[0], v1 = s[1];
    half8 h = {(_Float16)v0.x, (_Float16)v0.y, (_Float16)v0.z, (_Float16)v0.w,
               (_Float16)v1.x, (_Float16)v1.y, (_Float16)v1.z, (_Float16)v1.w};
    *(half8*)(ws + IH_OFF + (size_t)ic * 16) = h;
  }
}

// ---------------- kernel 2: barrier-free fused GEMM + packed top-2 ----------
// grid (TQ/BM, NIS), block 256 = 4 waves; wave tile 64q x 64i (4x4 MFMAs,
// 64 AGPR acc). A half-K image in 32 KB LDS (two phases), B direct global
// with depth-2 register prefetch.
// LDS image (per phase): phys(row, c) = row*512 + ((c ^ (row&7))*16), c=0..31
// -> b128 fragment reads conflict-free (XOR bijects each 8-lane phase).
__global__ __launch_bounds__(256, 3) void score_kernel(char* __restrict__ ws) {
  __shared__ __align__(16) char sA[BM * 512];  // 32 KB: 64 rows x 256 fp16

  const int tid  = threadIdx.x;
  const int lane = tid & 63;
  const int wave = tid >> 6;
  const int quad = lane >> 4;
  const int l15  = lane & 15;
  const int qtile = blockIdx.x;
  const int isplit = blockIdx.y;

  // staging map: instr j, thread t -> phys = j*4096 + t*16
  //   row = j*8 + (t>>5), c' = t&31, logical c = c' ^ (row&7) = (t&31)^((t>>5)&7)
  const char* Qbase = ws + QH_OFF + (size_t)qtile * BM * 1024;
  const int trow = tid >> 5;                       // 0..7
  const int cx   = (tid & 31) ^ (trow & 7);
  const char* gQ = Qbase + trow * 1024 + cx * 16;  // + phase*512 + j*8192
  const int ldst = wave * 1024 + lane * 16;        // + j*4096

  // B fragment pointers: tile(ni) = isplit*16 + wave*4 + ni (fragment order)
  const char* Ibase = ws + IH_OFF;
  const char* bP[4];
#pragma unroll
  for (int ni = 0; ni < 4; ++ni)
    bP[ni] = Ibase + ((size_t)(isplit * 16 + wave * 4 + ni) * 16384) + lane * 16;

  // A fragment offsets: row = mi*16 + l15 -> mi*8192 + l15*512
  const int aRow = l15 * 512;
  const int swzl = l15 & 7;

  float4t acc[4][4];
#pragma unroll
  for (int mi = 0; mi < 4; ++mi)
#pragma unroll
    for (int ni = 0; ni < 4; ++ni) acc[mi][ni] = (float4t){0.f, 0.f, 0.f, 0.f};

  half8 aC[4], aN[4], bC[4], bN[4], bN2[4];
  // preload b(kk=0,1) while phase-0 staging is in flight
#pragma unroll
  for (int ni = 0; ni < 4; ++ni) bC[ni] = *(const half8*)(bP[ni]);
#pragma unroll
  for (int ni = 0; ni < 4; ++ni) bN[ni] = *(const half8*)(bP[ni] + 1024);

#pragma unroll
  for (int phase = 0; phase < 2; ++phase) {
    __syncthreads();  // phase 1: prior phase's a-frag reads complete
#pragma unroll
    for (int j = 0; j < 8; ++j)
      lds_load16(gQ + phase * 512 + j * 8192, sA + ldst + j * 4096);
    __syncthreads();  // staged image visible (compiler drains vmcnt)

    // preload a(kl=0)
    {
      const int c0 = (quad ^ swzl) << 4;
#pragma unroll
      for (int mi = 0; mi < 4; ++mi)
        aC[mi] = *(const half8*)(sA + aRow + mi * 8192 + c0);
    }

#pragma unroll
    for (int kl = 0; kl < KHALF; ++kl) {
      const int kk = phase * KHALF + kl;
      if (kl + 1 < KHALF) {
        const int cN = ((((kl + 1) << 2) + quad) ^ swzl) << 4;
#pragma unroll
        for (int mi = 0; mi < 4; ++mi)
          aN[mi] = *(const half8*)(sA + aRow + mi * 8192 + cN);
      }
      if (kk + 2 < 16) {     // depth-2: b for kk+2 issued 2 MFMA-blocks ahead
#pragma unroll
        for (int ni = 0; ni < 4; ++ni)
          bN2[ni] = *(const half8*)(bP[ni] + (kk + 2) * 1024);
      }
#pragma unroll
      for (int mi = 0; mi < 4; ++mi)
#pragma unroll
        for (int ni = 0; ni < 4; ++ni)
          acc[mi][ni] = __builtin_amdgcn_mfma_f32_16x16x32_f16(
              aC[mi], bC[ni], acc[mi][ni], 0, 0, 0);
      if (kl + 1 < KHALF) {
#pragma unroll
        for (int x = 0; x < 4; ++x) aC[x] = aN[x];
      }
#pragma unroll
      for (int x = 0; x < 4; ++x) bC[x] = bN[x];
      if (kk + 2 < 16) {
#pragma unroll
        for (int x = 0; x < 4; ++x) bN[x] = bN2[x];
      }
    }
  }

  // ---- epilogue: packed (score | 12-bit global idx) top-2 per query row ----
  // C row = quad*4+r, col = l15. item = isplit*256 + wave*64 + ni*16 + l15.
  float t1[16], t2[16];
#pragma unroll
  for (int s = 0; s < 16; ++s) { t1[s] = -1e30f; t2[s] = -1e30f; }

  const int locBase = isplit * 256 + wave * 64 + l15;
#pragma unroll
  for (int ni = 0; ni < 4; ++ni) {
    const int loc = locBase + ni * 16;
#pragma unroll
    for (int mi = 0; mi < 4; ++mi) {
#pragma unroll
      for (int r = 0; r < 4; ++r) {
        const int s = mi * 4 + r;
        const int pb = (__float_as_int(acc[mi][ni][r]) & 0xFFFFF000) | loc;
        const float pv = __int_as_float(pb);
        const float mn = fminf(t1[s], pv);
        t1[s] = fmaxf(t1[s], pv);
        t2[s] = fmaxf(t2[s], mn);
      }
    }
  }

  // 4-step butterfly across the 16-lane l15 group (pure fmin/fmax)
#pragma unroll
  for (int s = 0; s < 16; ++s) {
#pragma unroll
    for (int m = 1; m < 16; m <<= 1) {
      const float o1 = __shfl_xor(t1[s], m, 16);
      const float o2 = __shfl_xor(t2[s], m, 16);
      const float mn = fminf(t1[s], o1);
      t1[s] = fmaxf(t1[s], o1);
      t2[s] = fmaxf(fmaxf(t2[s], o2), mn);
    }
  }

  // writer: l15 == 0; entry = isplit*4 + wave. 64 entries per query.
  if (l15 == 0) {
    float2* part = (float2*)(ws + PART_OFF);
    const int e = isplit * 4 + wave;
#pragma unroll
    for (int s = 0; s < 16; ++s) {
      const int qrow = qtile * BM + (s >> 2) * 16 + quad * 4 + (s & 3);
      part[(size_t)qrow * 64 + e] = make_float2(t1[s], t2[s]);
    }
  }
}

// ---------------- kernel 3: merge partials + exact fp32 rescue --------------
// one wave per query: 64 packed entries (1/lane) -> global fp16 top-2.
// If the packed gap exceeds 0.25 (>>5 sigma of fp16+quant score error),
// candidate 1 is certainly the true argmax: skip the 2nd gather entirely
// (wave-uniform branch). Otherwise exact fp32 re-score of both.
__global__ __launch_bounds__(256) void rescue_kernel(
    const float* __restrict__ q, const float* __restrict__ items,
    const char* __restrict__ ws, float* __restrict__ out) {
  const int wave = threadIdx.x >> 6;
  const int lane = threadIdx.x & 63;
  const int qrow = blockIdx.x * 4 + wave;

  const float2* part = (const float2*)(ws + PART_OFF);
  float2 ent = part[(size_t)qrow * 64 + lane];  // coalesced 512B burst
  float t1 = ent.x, t2 = ent.y;

#pragma unroll
  for (int m = 1; m < 64; m <<= 1) {
    const float o1 = __shfl_xor(t1, m, 64);
    const float o2 = __shfl_xor(t2, m, 64);
    const float mn = fminf(t1, o1);
    t1 = fmaxf(t1, o1);
    t2 = fmaxf(fmaxf(t2, o2), mn);
  }
  const int c1i = __float_as_int(t1) & 0xFFF;
  const int c2i = __float_as_int(t2) & 0xFFF;
  const bool need2 = (t1 - t2) < 0.25f;   // wave-uniform

  const float4* qp = (const float4*)(q + (size_t)qrow * CD);
  const float4* p1 = (const float4*)(items + (size_t)c1i * CD);
  float4 qa = qp[lane * 2], qb = qp[lane * 2 + 1];
  float4 xa = p1[lane * 2], xb = p1[lane * 2 + 1];

  float d1 = qa.x * xa.x + qa.y * xa.y + qa.z * xa.z + qa.w * xa.w +
             qb.x * xb.x + qb.y * xb.y + qb.z * xb.z + qb.w * xb.w;
  float qq = qa.x * qa.x + qa.y * qa.y + qa.z * qa.z + qa.w * qa.w +
             qb.x * qb.x + qb.y * qb.y + qb.z * qb.z + qb.w * qb.w;
  float i1 = xa.x * xa.x + xa.y * xa.y + xa.z * xa.z + xa.w * xa.w +
             xb.x * xb.x + xb.y * xb.y + xb.z * xb.z + xb.w * xb.w;

#pragma unroll
  for (int m = 1; m < 64; m <<= 1) {
    d1 += __shfl_xor(d1, m, 64);
    qq += __shfl_xor(qq, m, 64);
    i1 += __shfl_xor(i1, m, 64);
  }

  float d = d1, nn = i1;
  if (need2) {
    const float4* p2 = (const float4*)(items + (size_t)c2i * CD);
    float4 ya = p2[lane * 2], yb = p2[lane * 2 + 1];
    float d2 = qa.x * ya.x + qa.y * ya.y + qa.z * ya.z + qa.w * ya.w +
               qb.x * yb.x + qb.y * yb.y + qb.z * yb.z + qb.w * yb.w;
    float i2 = ya.x * ya.x + ya.y * ya.y + ya.z * ya.z + ya.w * ya.w +
               yb.x * yb.x + yb.y * yb.y + yb.z * yb.z + yb.w * yb.w;
#pragma unroll
    for (int m = 1; m < 64; m <<= 1) {
      d2 += __shfl_xor(d2, m, 64);
      i2 += __shfl_xor(i2, m, 64);
    }
    const bool use2 = (d2 > d1) || (d2 == d1 && c2i < c1i);
    d  = use2 ? d2 : d1;
    nn = use2 ? i2 : i1;
  }

  if (lane == 0) {
    float nq = fmaxf(sqrtf(qq), 1e-12f);
    float np = fmaxf(sqrtf(nn), 1e-12f);
    out[qrow] = -(d / (nq * np));
  }
}

// ---------------------------------------------------------------------------
extern "C" void kernel_launch(void* const* d_in, const int* in_sizes, int n_in,
                              void* d_out, int out_size, void* d_ws,
                              size_t ws_size, hipStream_t stream) {
  const float* q  = (const float*)d_in[0];
  const float* it = (const float*)d_in[1];
  char* ws = (char*)d_ws;
  float* out = (float*)d_out;

  const int total = TQ * CD / 4 + MI * CD / 8;
  convert_kernel<<<(total + 255) / 256, 256, 0, stream>>>(q, it, ws);
  dim3 grid(TQ / BM, NIS);
  score_kernel<<<grid, 256, 0, stream>>>(ws);
  rescue_kernel<<<TQ / 4, 256, 0, stream>>>(q, it, ws, out);
}